// Round 7
// baseline (79.305 us; speedup 1.0000x reference)
//
#include <hip/hip_runtime.h>
#include <hip/hip_bf16.h>

#define BB 4
#define NN 512
#define EE 256
#define HH 8
#define DD 32
#define SCALING 0.17677669529663687f  // 32^-0.5
#define PR 8   // rows per proj block
#define RR 4   // rows per logits block
#define HPB 2  // heads per logits block (blockIdx.y covers HH/HPB groups)

// ---------------------------------------------------------------------------
// Projection, one W per block (blockIdx.y: 0=Q,1=K,2=V).  Q pre-scaled
// [b,n,e]; K row-major per head Kp[((b*H+h)*N+m)*D+d]; V folded against
// Wf1/2/3 -> vw[((b*H+h)*3+c)*N+m].  768 blocks.
// ---------------------------------------------------------------------------
__global__ __launch_bounds__(256) void proj_kernel(
    const float* __restrict__ query,
    const float* __restrict__ Wq, const float* __restrict__ bq,
    const float* __restrict__ Wk, const float* __restrict__ bk,
    const float* __restrict__ Wv, const float* __restrict__ bv,
    const float* __restrict__ Wf1, const float* __restrict__ Wf2,
    const float* __restrict__ Wf3,
    float* __restrict__ Q, float* __restrict__ Kp, float* __restrict__ vw)
{
    __shared__ alignas(16) float s[PR][EE];    // 8 KB
    __shared__ alignas(16) float sv[PR][EE];   // 8 KB (V blocks only)
    const int which = blockIdx.y;
    const int row0 = blockIdx.x * PR;
    const int tid = threadIdx.x;               // output column e

    {
        const float4* src = (const float4*)(query + row0 * EE);
        ((float4*)s)[tid]       = src[tid];
        ((float4*)s)[tid + 256] = src[tid + 256];
    }
    __syncthreads();

    const float* W  = (which == 0) ? Wq : (which == 1) ? Wk : Wv;
    const float* bb = (which == 0) ? bq : (which == 1) ? bk : bv;

    float acc[PR];
    #pragma unroll
    for (int r = 0; r < PR; ++r) acc[r] = 0.f;

    const float4* W4 = (const float4*)(W + tid * EE);
    for (int j = 0; j < EE / 4; ++j) {
        const float4 w = W4[j];
        #pragma unroll
        for (int r = 0; r < PR; ++r) {
            const float4 x = *(const float4*)&s[r][4 * j];
            acc[r] += x.x * w.x + x.y * w.y + x.z * w.z + x.w * w.w;
        }
    }
    const float bbv = bb[tid];

    if (which == 0) {
        #pragma unroll
        for (int r = 0; r < PR; ++r)
            Q[(row0 + r) * EE + tid] = (acc[r] + bbv) * SCALING;
    } else if (which == 1) {
        const int h = tid >> 5, d = tid & 31;
        #pragma unroll
        for (int r = 0; r < PR; ++r) {
            const int grow = row0 + r;
            const int b = grow >> 9, n = grow & 511;
            Kp[((size_t)(b * HH + h) * NN + n) * DD + d] = acc[r] + bbv;
        }
    } else {
        #pragma unroll
        for (int r = 0; r < PR; ++r) sv[r][tid] = acc[r] + bbv;
        __syncthreads();
        if (tid < PR * 24) {                   // 192 threads: (r, h, c)
            const int r = tid / 24;
            const int rem = tid % 24;
            const int hh = rem / 3;
            const int c = rem % 3;
            const float* Wf = (c == 0) ? Wf1 : (c == 1) ? Wf2 : Wf3;
            float a = 0.f;
            #pragma unroll
            for (int dd = 0; dd < DD; ++dd)
                a += sv[r][hh * DD + dd] * Wf[hh * DD + dd];
            const int grow = row0 + r;
            const int b = grow >> 9, m = grow & 511;
            vw[((b * HH + hh) * 3 + c) * NN + m] = a;
        }
    }
}

// ---------------------------------------------------------------------------
// Logits: per head, e = exp(q.k + bias) -> P' (bf16) + per-wave S partials.
// Barrier-free, LDS-free.  Heads split across blockIdx.y for occupancy:
// grid (512, HH/HPB) = 2048 blocks = 2x machine wave capacity.
// ---------------------------------------------------------------------------
__global__ __launch_bounds__(512) void logits_kernel(
    const float* __restrict__ Q, const float* __restrict__ Kp,
    const float* __restrict__ attn_bias,
    __hip_bfloat16* __restrict__ Pp, float* __restrict__ Spart)
{
    const int blk = blockIdx.x;                // 512 blocks in x
    const int b = blk >> 7;
    const int n0 = (blk & 127) * RR;
    const int h0 = blockIdx.y * HPB;
    const int m = threadIdx.x;                 // column m
    const int wv = m >> 6, ln = m & 63;

    #pragma unroll
    for (int hi = 0; hi < HPB; ++hi) {
        const int h = h0 + hi;
        const float4* kp4 =
            (const float4*)(Kp + ((size_t)((b * HH + h) * NN) + m) * DD);
        float4 k4[DD / 4];
        #pragma unroll
        for (int j = 0; j < DD / 4; ++j) k4[j] = kp4[j];

        const size_t bias_base = ((size_t)(b * HH + h) * NN + n0) * NN + m;
        const float* qb = Q + (b * NN + n0) * EE + h * DD;  // block-uniform

        float e[RR];
        #pragma unroll
        for (int r = 0; r < RR; ++r) {
            float l = attn_bias[bias_base + (size_t)r * NN];
            #pragma unroll
            for (int j = 0; j < DD / 4; ++j) {
                const float4 q = *(const float4*)(qb + r * EE + 4 * j);
                l += k4[j].x * q.x + k4[j].y * q.y + k4[j].z * q.z + k4[j].w * q.w;
            }
            e[r] = __expf(l);                  // |l| ~ 10 << 88: safe
        }

        #pragma unroll
        for (int r = 0; r < RR; ++r)
            Pp[((size_t)(b * HH + h) * NN + (n0 + r)) * NN + m] =
                __float2bfloat16(e[r]);

        #pragma unroll
        for (int r = 0; r < RR; ++r) {
            float x = e[r];
            #pragma unroll
            for (int off = 32; off; off >>= 1)
                x += __shfl_xor(x, off, 64);
            if (ln == 0)
                Spart[((size_t)(b * HH + h) * NN + (n0 + r)) * 8 + wv] = x;
        }
    }
}

// ---------------------------------------------------------------------------
// Contract: per (b,n): fold S partials -> rcpS; A_c = sum_h P'*vw_c*rcpS;
// apply delta/mask; 3 block reductions; output.
// ---------------------------------------------------------------------------
__global__ __launch_bounds__(512) void contract_kernel(
    const __hip_bfloat16* __restrict__ Pp, const float* __restrict__ Spart,
    const float* __restrict__ vw, const float* __restrict__ delta_pos,
    const int* __restrict__ drop_edge_mask, const int* __restrict__ drop_or_add,
    const float* __restrict__ bf1, const float* __restrict__ bf2,
    const float* __restrict__ bf3, float* __restrict__ out)
{
    const int blk = blockIdx.x;                // 2048 blocks
    const int b = blk >> 9, n = blk & 511;
    const int m = threadIdx.x;
    const int wv = m >> 6, ln = m & 63;

    __shared__ float sred[64];
    __shared__ float srcp[HH];
    __shared__ float r3[3][8];

    if (m < 64)
        sred[m] = Spart[((size_t)(b * HH + (m >> 3)) * NN + n) * 8 + (m & 7)];
    __syncthreads();
    if (m < HH) {
        float s = 0.f;
        #pragma unroll
        for (int w = 0; w < 8; ++w) s += sred[m * 8 + w];
        srcp[m] = __builtin_amdgcn_rcpf(s);
    }
    __syncthreads();

    float A0 = 0.f, A1 = 0.f, A2 = 0.f;
    #pragma unroll
    for (int h = 0; h < HH; ++h) {
        const float p =
            __bfloat162float(Pp[((size_t)(b * HH + h) * NN + n) * NN + m]) *
            srcp[h];
        const float* vwp = vw + (b * HH + h) * 3 * NN + m;
        A0 += p * vwp[0];
        A1 += p * vwp[NN];
        A2 += p * vwp[2 * NN];
    }

    const float mk =
        (drop_or_add[0] != 0 && drop_edge_mask[n * NN + m] != 0) ? 0.f : 1.f;
    const float* dp = delta_pos + ((size_t)(b * NN + n) * NN + m) * 3;
    float v0 = A0 * dp[0] * mk;
    float v1 = A1 * dp[1] * mk;
    float v2 = A2 * dp[2] * mk;
    #pragma unroll
    for (int off = 32; off; off >>= 1) {
        v0 += __shfl_xor(v0, off, 64);
        v1 += __shfl_xor(v1, off, 64);
        v2 += __shfl_xor(v2, off, 64);
    }
    if (ln == 0) { r3[0][wv] = v0; r3[1][wv] = v1; r3[2][wv] = v2; }
    __syncthreads();

    if (m < 3) {
        float s = 0.f;
        #pragma unroll
        for (int w = 0; w < 8; ++w) s += r3[m][w];
        const float bias = (m == 0) ? bf1[0] : (m == 1) ? bf2[0] : bf3[0];
        out[(b * NN + n) * 3 + m] = s + bias;
    }
}

// ---------------------------------------------------------------------------
extern "C" void kernel_launch(void* const* d_in, const int* in_sizes, int n_in,
                              void* d_out, int out_size, void* d_ws, size_t ws_size,
                              hipStream_t stream)
{
    const float* query          = (const float*)d_in[0];
    const float* attn_bias      = (const float*)d_in[1];
    const float* delta_pos      = (const float*)d_in[2];
    const int*   drop_edge_mask = (const int*)d_in[3];
    const float* Wq  = (const float*)d_in[4];
    const float* bq  = (const float*)d_in[5];
    const float* Wk  = (const float*)d_in[6];
    const float* bk  = (const float*)d_in[7];
    const float* Wv  = (const float*)d_in[8];
    const float* bv  = (const float*)d_in[9];
    const float* Wf1 = (const float*)d_in[10];
    const float* bf1 = (const float*)d_in[11];
    const float* Wf2 = (const float*)d_in[12];
    const float* bf2 = (const float*)d_in[13];
    const float* Wf3 = (const float*)d_in[14];
    const float* bf3 = (const float*)d_in[15];
    const int*   drop_or_add = (const int*)d_in[16];

    float* ws = (float*)d_ws;
    float* Q     = ws;                     // 524288 floats
    float* Kp    = ws + 524288;            // 524288 floats
    float* vw    = ws + 1048576;           // 49152 floats
    float* Spart = ws + 1097728;           // B*H*N*8 = 131072 floats
    __hip_bfloat16* Pp = (__hip_bfloat16*)(ws + 1228800);  // B*H*N*N bf16 = 16.8 MB

    proj_kernel<<<dim3(BB * NN / PR, 3), 256, 0, stream>>>(
        query, Wq, bq, Wk, bk, Wv, bv, Wf1, Wf2, Wf3, Q, Kp, vw);
    logits_kernel<<<dim3(BB * NN / RR, HH / HPB), 512, 0, stream>>>(
        Q, Kp, attn_bias, Pp, Spart);
    contract_kernel<<<BB * NN, 512, 0, stream>>>(Pp, Spart, vw, delta_pos,
                                                 drop_edge_mask, drop_or_add,
                                                 bf1, bf2, bf3, (float*)d_out);
}

// Round 8
// 64.241 us; speedup vs baseline: 1.2345x; 1.2345x over previous
//
#include <hip/hip_runtime.h>
#include <hip/hip_bf16.h>

#define BB 4
#define NN 512
#define EE 256
#define HH 8
#define DD 32
#define SCALING 0.17677669529663687f  // 32^-0.5
#define PR 8   // rows per proj block
#define RR 4   // rows per logits block
#define HPB 2  // heads per logits block (blockIdx.y covers HH/HPB groups)

// ---------------------------------------------------------------------------
// Projection, one W per block (blockIdx.y: 0=Q,1=K,2=V).  Q pre-scaled
// [b,n,e]; K transposed Kt[((b*H+h)*D+d)*N+n] (coalesced reads in logits);
// V folded against Wf1/2/3 -> vw[((b*H+h)*3+c)*N+m].  768 blocks.
// ---------------------------------------------------------------------------
__global__ __launch_bounds__(256) void proj_kernel(
    const float* __restrict__ query,
    const float* __restrict__ Wq, const float* __restrict__ bq,
    const float* __restrict__ Wk, const float* __restrict__ bk,
    const float* __restrict__ Wv, const float* __restrict__ bv,
    const float* __restrict__ Wf1, const float* __restrict__ Wf2,
    const float* __restrict__ Wf3,
    float* __restrict__ Q, float* __restrict__ Kt, float* __restrict__ vw)
{
    __shared__ alignas(16) float s[PR][EE];    // 8 KB
    __shared__ alignas(16) float sv[PR][EE];   // 8 KB (V blocks only)
    const int which = blockIdx.y;
    const int row0 = blockIdx.x * PR;
    const int tid = threadIdx.x;               // output column e

    {
        const float4* src = (const float4*)(query + row0 * EE);
        ((float4*)s)[tid]       = src[tid];
        ((float4*)s)[tid + 256] = src[tid + 256];
    }
    __syncthreads();

    const float* W  = (which == 0) ? Wq : (which == 1) ? Wk : Wv;
    const float* bb = (which == 0) ? bq : (which == 1) ? bk : bv;

    float acc[PR];
    #pragma unroll
    for (int r = 0; r < PR; ++r) acc[r] = 0.f;

    const float4* W4 = (const float4*)(W + tid * EE);
    for (int j = 0; j < EE / 4; ++j) {
        const float4 w = W4[j];
        #pragma unroll
        for (int r = 0; r < PR; ++r) {
            const float4 x = *(const float4*)&s[r][4 * j];
            acc[r] += x.x * w.x + x.y * w.y + x.z * w.z + x.w * w.w;
        }
    }
    const float bbv = bb[tid];

    if (which == 0) {
        #pragma unroll
        for (int r = 0; r < PR; ++r)
            Q[(row0 + r) * EE + tid] = (acc[r] + bbv) * SCALING;
    } else if (which == 1) {
        const int h = tid >> 5, d = tid & 31;
        #pragma unroll
        for (int r = 0; r < PR; ++r) {
            const int grow = row0 + r;
            const int b = grow >> 9, n = grow & 511;
            Kt[((size_t)(b * HH + h) * DD + d) * NN + n] = acc[r] + bbv;
        }
    } else {
        #pragma unroll
        for (int r = 0; r < PR; ++r) sv[r][tid] = acc[r] + bbv;
        __syncthreads();
        if (tid < PR * 24) {                   // 192 threads: (r, h, c)
            const int r = tid / 24;
            const int rem = tid % 24;
            const int hh = rem / 3;
            const int c = rem % 3;
            const float* Wf = (c == 0) ? Wf1 : (c == 1) ? Wf2 : Wf3;
            float a = 0.f;
            #pragma unroll
            for (int dd = 0; dd < DD; ++dd)
                a += sv[r][hh * DD + dd] * Wf[hh * DD + dd];
            const int grow = row0 + r;
            const int b = grow >> 9, m = grow & 511;
            vw[((b * HH + hh) * 3 + c) * NN + m] = a;
        }
    }
}

// ---------------------------------------------------------------------------
// Logits: per head, e = exp(q.k + bias) -> P' (bf16) + per-wave S partials.
// Barrier-free, LDS-free.  K read COALESCED from Kt (lane m -> 4B at
// consecutive addresses): 32 x 2-line loads/head vs 8 x 64-line before.
// ---------------------------------------------------------------------------
__global__ __launch_bounds__(512) void logits_kernel(
    const float* __restrict__ Q, const float* __restrict__ Kt,
    const float* __restrict__ attn_bias,
    __hip_bfloat16* __restrict__ Pp, float* __restrict__ Spart)
{
    const int blk = blockIdx.x;                // 512 blocks in x
    const int b = blk >> 7;
    const int n0 = (blk & 127) * RR;
    const int h0 = blockIdx.y * HPB;
    const int m = threadIdx.x;                 // column m
    const int wv = m >> 6, ln = m & 63;

    #pragma unroll
    for (int hi = 0; hi < HPB; ++hi) {
        const int h = h0 + hi;
        const float* kp = Kt + ((size_t)(b * HH + h) * DD) * NN + m;
        float kreg[DD];
        #pragma unroll
        for (int d = 0; d < DD; ++d) kreg[d] = kp[(size_t)d * NN];

        const size_t bias_base = ((size_t)(b * HH + h) * NN + n0) * NN + m;
        const float* qb = Q + (b * NN + n0) * EE + h * DD;  // block-uniform

        float e[RR];
        #pragma unroll
        for (int r = 0; r < RR; ++r) {
            float l = attn_bias[bias_base + (size_t)r * NN];
            #pragma unroll
            for (int d = 0; d < DD; ++d)
                l += qb[r * EE + d] * kreg[d];
            e[r] = __expf(l);                  // |l| ~ 10 << 88: safe
        }

        #pragma unroll
        for (int r = 0; r < RR; ++r)
            Pp[((size_t)(b * HH + h) * NN + (n0 + r)) * NN + m] =
                __float2bfloat16(e[r]);

        #pragma unroll
        for (int r = 0; r < RR; ++r) {
            float x = e[r];
            #pragma unroll
            for (int off = 32; off; off >>= 1)
                x += __shfl_xor(x, off, 64);
            if (ln == 0)
                Spart[((size_t)(b * HH + h) * NN + (n0 + r)) * 8 + wv] = x;
        }
    }
}

// ---------------------------------------------------------------------------
// Contract: per (b,n): fold S partials -> rcpS; A_c = sum_h P'*vw_c*rcpS;
// apply delta/mask (delta staged coalesced through LDS); 3 block reductions.
// ---------------------------------------------------------------------------
__global__ __launch_bounds__(512) void contract_kernel(
    const __hip_bfloat16* __restrict__ Pp, const float* __restrict__ Spart,
    const float* __restrict__ vw, const float* __restrict__ delta_pos,
    const int* __restrict__ drop_edge_mask, const int* __restrict__ drop_or_add,
    const float* __restrict__ bf1, const float* __restrict__ bf2,
    const float* __restrict__ bf3, float* __restrict__ out)
{
    const int blk = blockIdx.x;                // 2048 blocks
    const int b = blk >> 9, n = blk & 511;
    const int m = threadIdx.x;
    const int wv_id = m >> 6, ln = m & 63;

    __shared__ float sred[64];
    __shared__ float srcp[HH];
    __shared__ float r3[3][8];
    __shared__ float sdp[3 * NN];              // 6 KB staged delta row

    // coalesced stage of delta_pos row (1536 contiguous floats)
    {
        const float* dpb = delta_pos + (size_t)(b * NN + n) * NN * 3;
        sdp[m]        = dpb[m];
        sdp[m + 512]  = dpb[m + 512];
        sdp[m + 1024] = dpb[m + 1024];
    }
    if (m < 64)
        sred[m] = Spart[((size_t)(b * HH + (m >> 3)) * NN + n) * 8 + (m & 7)];
    __syncthreads();
    if (m < HH) {
        float s = 0.f;
        #pragma unroll
        for (int w = 0; w < 8; ++w) s += sred[m * 8 + w];
        srcp[m] = __builtin_amdgcn_rcpf(s);
    }
    __syncthreads();

    float A0 = 0.f, A1 = 0.f, A2 = 0.f;
    #pragma unroll
    for (int h = 0; h < HH; ++h) {
        const float p =
            __bfloat162float(Pp[((size_t)(b * HH + h) * NN + n) * NN + m]) *
            srcp[h];
        const float* vwp = vw + (b * HH + h) * 3 * NN + m;
        A0 += p * vwp[0];
        A1 += p * vwp[NN];
        A2 += p * vwp[2 * NN];
    }

    const float mk =
        (drop_or_add[0] != 0 && drop_edge_mask[n * NN + m] != 0) ? 0.f : 1.f;
    float v0 = A0 * sdp[3 * m + 0] * mk;
    float v1 = A1 * sdp[3 * m + 1] * mk;
    float v2 = A2 * sdp[3 * m + 2] * mk;
    #pragma unroll
    for (int off = 32; off; off >>= 1) {
        v0 += __shfl_xor(v0, off, 64);
        v1 += __shfl_xor(v1, off, 64);
        v2 += __shfl_xor(v2, off, 64);
    }
    if (ln == 0) { r3[0][wv_id] = v0; r3[1][wv_id] = v1; r3[2][wv_id] = v2; }
    __syncthreads();

    if (m < 3) {
        float s = 0.f;
        #pragma unroll
        for (int w = 0; w < 8; ++w) s += r3[m][w];
        const float bias = (m == 0) ? bf1[0] : (m == 1) ? bf2[0] : bf3[0];
        out[(b * NN + n) * 3 + m] = s + bias;
    }
}

// ---------------------------------------------------------------------------
extern "C" void kernel_launch(void* const* d_in, const int* in_sizes, int n_in,
                              void* d_out, int out_size, void* d_ws, size_t ws_size,
                              hipStream_t stream)
{
    const float* query          = (const float*)d_in[0];
    const float* attn_bias      = (const float*)d_in[1];
    const float* delta_pos      = (const float*)d_in[2];
    const int*   drop_edge_mask = (const int*)d_in[3];
    const float* Wq  = (const float*)d_in[4];
    const float* bq  = (const float*)d_in[5];
    const float* Wk  = (const float*)d_in[6];
    const float* bk  = (const float*)d_in[7];
    const float* Wv  = (const float*)d_in[8];
    const float* bv  = (const float*)d_in[9];
    const float* Wf1 = (const float*)d_in[10];
    const float* bf1 = (const float*)d_in[11];
    const float* Wf2 = (const float*)d_in[12];
    const float* bf2 = (const float*)d_in[13];
    const float* Wf3 = (const float*)d_in[14];
    const float* bf3 = (const float*)d_in[15];
    const int*   drop_or_add = (const int*)d_in[16];

    float* ws = (float*)d_ws;
    float* Q     = ws;                     // 524288 floats
    float* Kt    = ws + 524288;            // 524288 floats
    float* vw    = ws + 1048576;           // 49152 floats
    float* Spart = ws + 1097728;           // B*H*N*8 = 131072 floats
    __hip_bfloat16* Pp = (__hip_bfloat16*)(ws + 1228800);  // B*H*N*N bf16 = 16.8 MB

    proj_kernel<<<dim3(BB * NN / PR, 3), 256, 0, stream>>>(
        query, Wq, bq, Wk, bk, Wv, bv, Wf1, Wf2, Wf3, Q, Kt, vw);
    logits_kernel<<<dim3(BB * NN / RR, HH / HPB), 512, 0, stream>>>(
        Q, Kt, attn_bias, Pp, Spart);
    contract_kernel<<<BB * NN, 512, 0, stream>>>(Pp, Spart, vw, delta_pos,
                                                 drop_edge_mask, drop_or_add,
                                                 bf1, bf2, bf3, (float*)d_out);
}